// Round 6
// baseline (178.603 us; speedup 1.0000x reference)
//
#include <hip/hip_runtime.h>
#include <hip/hip_bf16.h>
#include <stdint.h>

#define S_ATOMS 25
#define DIM 64
#define AP 40      // hT row stride (shorts): 80B rows
#define VP 72      // v' row stride (shorts): 144B rows
#define WAVES 4    // waves per block
#define XB2 2560   // shorts per (wave,mol) buffer: max(64*AP, 32*VP)

typedef __attribute__((ext_vector_type(8))) short short8;   // 8 bf16
typedef __attribute__((ext_vector_type(4))) short short4s;  // 4 bf16 (b64)
typedef __attribute__((ext_vector_type(4))) float f32x4;

static __device__ __forceinline__ short bf(float x) {
    return (short)__builtin_bit_cast(unsigned short, __float2bfloat16(x));
}

// ---------------- phase A (one kernel): prep_w + edge histogram -------------
// Bg nibble index n = mol*625 + dl*25 + sl ; counts Poisson(0.16) -> never >=16
__global__ __launch_bounds__(256) void phaseA_k(
    const float* __restrict__ W_fp, const int* __restrict__ esrc,
    const int* __restrict__ edst, unsigned* __restrict__ Bg,
    short* __restrict__ wpk, int LH, int E)
{
    int gid = blockIdx.x * 256 + threadIdx.x;
    if (gid < LH * 512) {
        int t = gid;
        int layer = t >> 9, q = t & 511;
        int nt = q >> 7, ks = (q >> 6) & 1, lane = q & 63;
        int cc = lane & 15, gg = lane >> 4;
        const float* p = W_fp + (size_t)layer * 4096 + (nt * 16 + cc) * 64 + ks * 32 + 8 * gg;
        short8 s;
        #pragma unroll
        for (int j = 0; j < 8; ++j) s[j] = bf(p[j]);
        *(short8*)(wpk + (size_t)t * 8) = s;
    }
    if (gid < E) {
        int s = esrc[gid], d = edst[gid];
        int m  = s / S_ATOMS;
        int sl = s - m * S_ATOMS;
        int dl = d - m * S_ATOMS;
        int n = m * 625 + dl * 25 + sl;
        atomicAdd(&Bg[n >> 3], 1u << ((n & 7) * 4));
    }
}

// ---------------- per-wave: process 2 molecules, fully interleaved ----------
static __device__ __forceinline__ void process_batch(
    int mol0, int mol1, bool hasB,
    const float* __restrict__ emb, const float* __restrict__ b_fp,
    const float* __restrict__ W_out, const float* __restrict__ b_out,
    const float* __restrict__ W_prop, const float* __restrict__ b_prop,
    const int* __restrict__ fps, const unsigned* __restrict__ Bg,
    const short8* __restrict__ wp8, float* __restrict__ out,
    int LH, int LO,
    short* xb0, short* xb1, float* mv0, float* mv1,
    int l, int c, int g)
{
    const int mol[2] = {mol0, mol1};
    short* const xb[2] = {xb0, xb1};
    float* const mv[2] = {mv0, mv1};

    // ---- amat: B^T-operand frags, B = I + A, from nibble histogram ----
    short8 amat[2][2];
    #pragma unroll
    for (int q = 0; q < 2; ++q)
        #pragma unroll
        for (int at = 0; at < 2; ++at) {
            int row = at * 16 + c;
            float f[8];
            if (row < S_ATOMS) {
                int n0 = mol[q] * 625 + row * 25 + 8 * g;
                unsigned lo = Bg[n0 >> 3], hi = Bg[(n0 >> 3) + 1];
                unsigned long long v64 = ((unsigned long long)hi << 32) | lo;
                v64 >>= ((n0 & 7) * 4);
                #pragma unroll
                for (int j = 0; j < 8; ++j) {
                    unsigned n = (unsigned)(v64 >> (4 * j)) & 0xFu;
                    f[j] = (8 * g + j) < S_ATOMS ? (float)n : 0.f;
                    if (8 * g + j == row) f[j] += 1.0f;
                }
            } else {
                #pragma unroll
                for (int j = 0; j < 8; ++j) f[j] = 0.f;
            }
            short8 s;
            #pragma unroll
            for (int j = 0; j < 8; ++j) s[j] = bf(f[j]);
            amat[q][at] = s;
        }

    // ---- layer-0 A-frags from the f32 embedding table ----
    short8 a1[2][2][2];
    #pragma unroll
    for (int q = 0; q < 2; ++q)
        #pragma unroll
        for (int mt = 0; mt < 2; ++mt) {
            int atom = mt * 16 + c;
            int aa = atom < S_ATOMS ? atom : S_ATOMS - 1;  // pads killed by B cols=0
            int fi = fps[mol[q] * S_ATOMS + aa];
            const float* row = emb + (size_t)fi * DIM;
            #pragma unroll
            for (int ks = 0; ks < 2; ++ks) {
                const float4* qp = (const float4*)(row + ks * 32 + 8 * g);
                float4 f0 = qp[0], f1 = qp[1];
                short8 s;
                s[0]=bf(f0.x); s[1]=bf(f0.y); s[2]=bf(f0.z); s[3]=bf(f0.w);
                s[4]=bf(f1.x); s[5]=bf(f1.y); s[6]=bf(f1.z); s[7]=bf(f1.w);
                a1[q][mt][ks] = s;
            }
        }

    for (int layer = 0; layer < LH; ++layer) {
        // ---- GEMM1 (both mols): acc = v*W^T + b ----
        float bv[4];
        #pragma unroll
        for (int nt = 0; nt < 4; ++nt) bv[nt] = b_fp[layer * DIM + nt * 16 + c];
        f32x4 acc[2][2][4];
        #pragma unroll
        for (int q = 0; q < 2; ++q)
            #pragma unroll
            for (int mt = 0; mt < 2; ++mt)
                #pragma unroll
                for (int nt = 0; nt < 4; ++nt) {
                    f32x4 a; a[0]=bv[nt]; a[1]=bv[nt]; a[2]=bv[nt]; a[3]=bv[nt];
                    acc[q][mt][nt] = a;
                }
        #pragma unroll
        for (int ks = 0; ks < 2; ++ks) {
            short8 bwk[4];
            #pragma unroll
            for (int nt = 0; nt < 4; ++nt)
                bwk[nt] = wp8[layer * 512 + nt * 128 + ks * 64 + l];
            #pragma unroll
            for (int q = 0; q < 2; ++q)
                #pragma unroll
                for (int mt = 0; mt < 2; ++mt)
                    #pragma unroll
                    for (int nt = 0; nt < 4; ++nt)
                        acc[q][mt][nt] = __builtin_amdgcn_mfma_f32_16x16x32_bf16(
                            a1[q][mt][ks], bwk[nt], acc[q][mt][nt], 0, 0, 0);
        }

        // ---- epilogue1: relu, pack, write hT[dout][atom] for both mols ----
        #pragma unroll
        for (int q = 0; q < 2; ++q)
            #pragma unroll
            for (int mt = 0; mt < 2; ++mt)
                #pragma unroll
                for (int nt = 0; nt < 4; ++nt) {
                    short4s p;
                    p[0] = bf(fmaxf(acc[q][mt][nt][0], 0.f));
                    p[1] = bf(fmaxf(acc[q][mt][nt][1], 0.f));
                    p[2] = bf(fmaxf(acc[q][mt][nt][2], 0.f));
                    p[3] = bf(fmaxf(acc[q][mt][nt][3], 0.f));
                    *(short4s*)&xb[q][(nt * 16 + c) * AP + mt * 16 + 4 * g] = p;
                }
        __builtin_amdgcn_wave_barrier();

        // ---- GEMM2: u^T = h^T * B^T ----
        short8 b2[2][4];
        #pragma unroll
        for (int q = 0; q < 2; ++q)
            #pragma unroll
            for (int dt = 0; dt < 4; ++dt)
                b2[q][dt] = *(const short8*)&xb[q][(dt * 16 + c) * AP + 8 * g];
        f32x4 ua[2][4][2];
        #pragma unroll
        for (int q = 0; q < 2; ++q)
            #pragma unroll
            for (int dt = 0; dt < 4; ++dt)
                #pragma unroll
                for (int at = 0; at < 2; ++at) {
                    f32x4 z; z[0]=0.f; z[1]=0.f; z[2]=0.f; z[3]=0.f;
                    ua[q][dt][at] = __builtin_amdgcn_mfma_f32_16x16x32_bf16(
                        b2[q][dt], amat[q][at], z, 0, 0, 0);
                }

        // ---- per-atom norms ----
        float rn[2][2];
        #pragma unroll
        for (int q = 0; q < 2; ++q) {
            float ss0 = 0.f, ss1 = 0.f;
            #pragma unroll
            for (int dt = 0; dt < 4; ++dt)
                #pragma unroll
                for (int r = 0; r < 4; ++r) {
                    ss0 += ua[q][dt][0][r] * ua[q][dt][0][r];
                    ss1 += ua[q][dt][1][r] * ua[q][dt][1][r];
                }
            ss0 += __shfl_xor(ss0, 16); ss0 += __shfl_xor(ss0, 32);
            ss1 += __shfl_xor(ss1, 16); ss1 += __shfl_xor(ss1, 32);
            rn[q][0] = __builtin_amdgcn_rsqf(fmaxf(ss0, 1e-24f));
            rn[q][1] = __builtin_amdgcn_rsqf(fmaxf(ss1, 1e-24f));
        }
        __builtin_amdgcn_wave_barrier();

        if (layer != LH - 1) {
            // ---- v' -> xb[atom][dim] (overlays hT; b2 already in regs) ----
            #pragma unroll
            for (int q = 0; q < 2; ++q)
                #pragma unroll
                for (int at = 0; at < 2; ++at) {
                    float r0 = rn[q][at];
                    #pragma unroll
                    for (int dt = 0; dt < 4; ++dt) {
                        short4s p;
                        p[0] = bf(ua[q][dt][at][0] * r0);
                        p[1] = bf(ua[q][dt][at][1] * r0);
                        p[2] = bf(ua[q][dt][at][2] * r0);
                        p[3] = bf(ua[q][dt][at][3] * r0);
                        *(short4s*)&xb[q][(at * 16 + c) * VP + dt * 16 + 4 * g] = p;
                    }
                }
            __builtin_amdgcn_wave_barrier();
            #pragma unroll
            for (int q = 0; q < 2; ++q)
                #pragma unroll
                for (int mt = 0; mt < 2; ++mt)
                    #pragma unroll
                    for (int ks = 0; ks < 2; ++ks)
                        a1[q][mt][ks] = *(const short8*)&xb[q][(mt * 16 + c) * VP + ks * 32 + 8 * g];
        } else {
            // ---- molecule sum via 15-shfl split-butterfly over 16 c-lanes ----
            #pragma unroll
            for (int q = 0; q < 2; ++q) {
                float mx[16];
                #pragma unroll
                for (int dt = 0; dt < 4; ++dt)
                    #pragma unroll
                    for (int r = 0; r < 4; ++r)
                        mx[dt * 4 + r] = ua[q][dt][0][r] * rn[q][0] + ua[q][dt][1][r] * rn[q][1];
                #pragma unroll
                for (int k = 0; k < 8; ++k) {
                    float send = (c & 8) ? mx[k] : mx[k + 8];
                    float keep = (c & 8) ? mx[k + 8] : mx[k];
                    mx[k] = keep + __shfl_xor(send, 8);
                }
                #pragma unroll
                for (int k = 0; k < 4; ++k) {
                    float send = (c & 4) ? mx[k] : mx[k + 4];
                    float keep = (c & 4) ? mx[k + 4] : mx[k];
                    mx[k] = keep + __shfl_xor(send, 4);
                }
                #pragma unroll
                for (int k = 0; k < 2; ++k) {
                    float send = (c & 2) ? mx[k] : mx[k + 2];
                    float keep = (c & 2) ? mx[k + 2] : mx[k];
                    mx[k] = keep + __shfl_xor(send, 2);
                }
                {
                    float send = (c & 1) ? mx[0] : mx[1];
                    float keep = (c & 1) ? mx[1] : mx[0];
                    mx[0] = keep + __shfl_xor(send, 1);
                }
                int dim = (c >> 2) * 16 + 4 * g + (c & 3);
                mv[q][dim] = mx[0];
            }
            __builtin_amdgcn_wave_barrier();
        }
    }

    // ---- output MLP for both molecules (lane = dout) ----
    float cur[2] = {0.f, 0.f};
    for (int layer = 0; layer < LO; ++layer) {
        const float4* wr = (const float4*)(W_out + ((size_t)layer * DIM + l) * DIM);
        float bb = b_out[layer * DIM + l];
        float av[2] = {bb, bb};
        #pragma unroll
        for (int k = 0; k < 16; ++k) {
            float4 ww = wr[k];
            #pragma unroll
            for (int q = 0; q < 2; ++q) {
                float4 vv = ((const float4*)mv[q])[k];
                av[q] += vv.x * ww.x + vv.y * ww.y + vv.z * ww.z + vv.w * ww.w;
            }
        }
        __builtin_amdgcn_wave_barrier();
        #pragma unroll
        for (int q = 0; q < 2; ++q) { cur[q] = fmaxf(av[q], 0.f); mv[q][l] = cur[q]; }
        __builtin_amdgcn_wave_barrier();
    }
    float wpv = W_prop[l], bp = b_prop[0];
    float p0 = cur[0] * wpv, p1 = cur[1] * wpv;
    #pragma unroll
    for (int o = 32; o; o >>= 1) { p0 += __shfl_xor(p0, o); p1 += __shfl_xor(p1, o); }
    if (l == 0) {
        out[mol0] = p0 + bp;
        if (hasB) out[mol1] = p1 + bp;
    }
}

// ---------------- phase B: static assignment, 8 molecules per block ---------
__global__ __launch_bounds__(256, 3) void gnn_k(
    const float* __restrict__ emb, const float* __restrict__ b_fp,
    const float* __restrict__ W_out, const float* __restrict__ b_out,
    const float* __restrict__ W_prop, const float* __restrict__ b_prop,
    const int* __restrict__ fps, const unsigned* __restrict__ Bg,
    const short* __restrict__ wpk,
    float* __restrict__ out, int LH, int LO, int M)
{
    __shared__ __align__(16) short xb_all[WAVES][2][XB2];
    __shared__ __align__(16) float mv_all[WAVES][2][DIM];
    const int w = threadIdx.x >> 6, l = threadIdx.x & 63;
    const int c = l & 15, g = l >> 4;
    int mA = (blockIdx.x * WAVES + w) * 2;
    if (mA >= M) return;                       // wave-uniform
    int mB = mA + 1;
    bool hasB = mB < M;
    if (!hasB) mB = mA;
    process_batch(mA, mB, hasB, emb, b_fp, W_out, b_out, W_prop, b_prop,
                  fps, Bg, (const short8*)wpk, out, LH, LO,
                  xb_all[w][0], xb_all[w][1], mv_all[w][0], mv_all[w][1], l, c, g);
}

// ---------------- launch ----------------------------------------------------
extern "C" void kernel_launch(void* const* d_in, const int* in_sizes, int n_in,
                              void* d_out, int out_size, void* d_ws, size_t ws_size,
                              hipStream_t stream)
{
    const float* emb    = (const float*)d_in[0];
    const float* W_fp   = (const float*)d_in[1];
    const float* b_fp   = (const float*)d_in[2];
    const float* W_out  = (const float*)d_in[3];
    const float* b_out  = (const float*)d_in[4];
    const float* W_prop = (const float*)d_in[5];
    const float* b_prop = (const float*)d_in[6];
    const int*   fps    = (const int*)d_in[7];
    const int*   esrc   = (const int*)d_in[8];
    const int*   edst   = (const int*)d_in[9];

    const int T  = in_sizes[7];
    const int E  = in_sizes[8];
    const int LH = in_sizes[1] / (DIM * DIM);
    const int LO = in_sizes[3] / (DIM * DIM);
    const int M  = T / S_ATOMS;

    // workspace: [Bg nibble hist | wpk prepacked W frags]
    size_t hist_bytes = (((size_t)M * 625 + 1) / 2 + 255) & ~(size_t)255;
    unsigned* Bg  = (unsigned*)d_ws;
    short*    wpk = (short*)((char*)d_ws + hist_bytes + 256);

    hipMemsetAsync(Bg, 0, hist_bytes + 16, stream);
    phaseA_k<<<(E + 255) / 256, 256, 0, stream>>>(W_fp, esrc, edst, Bg, wpk, LH, E);

    int grid = (M + WAVES * 2 - 1) / (WAVES * 2);
    gnn_k<<<grid, WAVES * 64, 0, stream>>>(emb, b_fp, W_out, b_out, W_prop, b_prop,
                                           fps, Bg, wpk, (float*)d_out, LH, LO, M);
}